// Round 2
// baseline (637.717 us; speedup 1.0000x reference)
//
#include <hip/hip_runtime.h>
#include <cstdint>

// Problem constants (fixed by reference):
#define Bc 1024
#define Tc 4096
#define Nc 2048
#define Kc 16
#define Mc 65536

// One block per batch row b. 256 threads.
// Phase 1: pack input_bits[b, :] (4096 int32 0/1) into a 4096-bit LDS bitset
//          via __ballot (wave64 -> one 64-bit mask per 64 elements).
// Phase 2: each thread handles 8 n values (n = i*256 + tid):
//          - coalesced int4 loads of connections[n, 0:16]
//          - 16 LDS bit tests -> 16-bit address
// Phase 3: random gather memory[n*65536 + addr] (the HBM/latency-bound part;
//          8 independent loads per thread for memory-level parallelism)
// Phase 4: coalesced int32 store of (val & 1)  [bool output -> int32 in harness]
__global__ __launch_bounds__(256) void ram_lookup_kernel(
    const int* __restrict__ input_bits,   // (B, T) int32 in {0,1}
    const int* __restrict__ connections,  // (N, K) int32 in [0, T)
    const int* __restrict__ memory,       // (N, M) int32
    int* __restrict__ out)                // (B, N) bool-as-int32
{
    __shared__ uint32_t bits[Tc / 32];    // 128 words = 512 B

    const int b    = blockIdx.x;
    const int tid  = threadIdx.x;
    const int lane = tid & 63;
    const int wave = tid >> 6;

    const int* row = input_bits + (size_t)b * Tc;

    // ---- Phase 1: build bitset ----
#pragma unroll
    for (int i = 0; i < Tc / 256; ++i) {          // 16 iterations
        const int pos = i * 256 + wave * 64 + lane;
        const unsigned long long m = __ballot(row[pos] & 1);
        if (lane == 0) {
            const int w64 = i * 4 + wave;          // 64-bit word index
            bits[w64 * 2]     = (uint32_t)m;
            bits[w64 * 2 + 1] = (uint32_t)(m >> 32);
        }
    }
    __syncthreads();

    // ---- Phase 2: addresses ----
    uint32_t addrs[Nc / 256];
#pragma unroll
    for (int i = 0; i < Nc / 256; ++i) {          // 8 iterations
        const int n = i * 256 + tid;
        const int4* cp = (const int4*)(connections + n * Kc);
        const int4 c0 = cp[0], c1 = cp[1], c2 = cp[2], c3 = cp[3];
        const int c[16] = {c0.x, c0.y, c0.z, c0.w,
                           c1.x, c1.y, c1.z, c1.w,
                           c2.x, c2.y, c2.z, c2.w,
                           c3.x, c3.y, c3.z, c3.w};
        uint32_t a = 0;
#pragma unroll
        for (int k = 0; k < 16; ++k) {
            const uint32_t t = (uint32_t)c[k];
            a |= ((bits[t >> 5] >> (t & 31)) & 1u) << k;
        }
        addrs[i] = a;
    }

    // ---- Phase 3: independent random gathers (MLP) ----
    int vals[Nc / 256];
#pragma unroll
    for (int i = 0; i < Nc / 256; ++i) {
        const int n = i * 256 + tid;
        vals[i] = memory[(size_t)n * Mc + addrs[i]];
    }

    // ---- Phase 4: coalesced int32 stores ----
#pragma unroll
    for (int i = 0; i < Nc / 256; ++i) {
        out[(size_t)b * Nc + i * 256 + tid] = vals[i] & 1;
    }
}

extern "C" void kernel_launch(void* const* d_in, const int* in_sizes, int n_in,
                              void* d_out, int out_size, void* d_ws, size_t ws_size,
                              hipStream_t stream) {
    const int* input_bits  = (const int*)d_in[0];  // B*T
    const int* connections = (const int*)d_in[1];  // N*K
    const int* memory      = (const int*)d_in[2];  // N*M
    int* out               = (int*)d_out;          // B*N (bool -> int32)

    hipLaunchKernelGGL(ram_lookup_kernel, dim3(Bc), dim3(256), 0, stream,
                       input_bits, connections, memory, out);
}